// Round 4
// baseline (271.922 us; speedup 1.0000x reference)
//
#include <hip/hip_runtime.h>

// points (P=8192, L=3072, 2) fp32. Per row: 1024 triplets (p1,p2,p3 strided 3),
// p4 = roll(p1, -1). Output: scalar mean over P*1024 = 2^23 xing values.
//
// Round-4 structure: block stages one full row (24 KB) into LDS via perfectly
// coalesced float4 loads (256 lanes x 16 B = 4 KB contiguous per instruction),
// then each thread computes 4 triplets from LDS. The roll() wrap is LDS-local.
// LDS is padded +4 words per 32 words: preserves 16 B alignment for b128 ops
// and breaks the 24-word thread stride to <=4-way bank conflicts.

#define NTHREADS 256
#define NBLOCKS  2048
#define ROW_FLOATS 6144                 // L*2
#define LDS_WORDS (ROW_FLOATS + (ROW_FLOATS / 32) * 4)   // 6912 words = 27.6 KB

__device__ __forceinline__ int pa(int w) { return w + ((w >> 5) << 2); }

__device__ __forceinline__ float xing1(float p1x, float p1y, float p2x, float p2y,
                                       float p3x, float p3y, float p4x, float p4y) {
    float v12x = p2x - p1x, v12y = p2y - p1y;
    float v23x = p3x - p2x, v23y = p3y - p2y;
    float v43x = p4x - p3x, v43y = p4y - p3y;
    float c1 = v12x * v23y - v12y * v23x;          // outer(v12, v23)
    float c2 = v12x * v43y - v12y * v43x;          // outer(v12, v43)
    float d12 = v12x * v12x + v12y * v12y;
    float d43 = v43x * v43x + v43y * v43y;
    // ref: D2 = c2 / (sqrt(d12)*sqrt(d43));  xing = relu(c1>0 ? -D2 : D2)
    float inv = __builtin_amdgcn_rsqf(d12 * d43);  // v_rsq_f32, inv > 0
    float s = (c1 > 0.0f) ? -c2 : c2;
    return fmaxf(s * inv, 0.0f);
}

__global__ __launch_bounds__(NTHREADS) void xing_partial(const float* __restrict__ pts,
                                                         float* __restrict__ partial,
                                                         int P) {
    __shared__ float lds[LDS_WORDS];
    const int tid = threadIdx.x;
    float acc = 0.0f;

    for (int row = blockIdx.x; row < P; row += NBLOCKS) {
        const float4* rowp = reinterpret_cast<const float4*>(pts + (size_t)row * ROW_FLOATS);

        // coalesced stage: 6 x (256 lanes x float4) = 24 KB contiguous
        #pragma unroll
        for (int i = 0; i < 6; ++i) {
            int idx = i * NTHREADS + tid;            // float4 index 0..1535
            float4 v = rowp[idx];
            *reinterpret_cast<float4*>(&lds[pa(idx * 4)]) = v;
        }
        __syncthreads();

        // each thread: 4 triplets = 24 floats starting at word a = tid*24
        int a = tid * 24;
        float4 q0 = *reinterpret_cast<const float4*>(&lds[pa(a)]);       // p1a p2a
        float4 q1 = *reinterpret_cast<const float4*>(&lds[pa(a + 4)]);   // p3a p1b
        float4 q2 = *reinterpret_cast<const float4*>(&lds[pa(a + 8)]);   // p2b p3b
        float4 q3 = *reinterpret_cast<const float4*>(&lds[pa(a + 12)]);  // p1c p2c
        float4 q4 = *reinterpret_cast<const float4*>(&lds[pa(a + 16)]);  // p3c p1d
        float4 q5 = *reinterpret_cast<const float4*>(&lds[pa(a + 20)]);  // p2d p3d
        int an = (tid == NTHREADS - 1) ? 0 : a + 24;                     // roll wrap
        float2 tl = *reinterpret_cast<const float2*>(&lds[pa(an)]);

        acc += xing1(q0.x, q0.y, q0.z, q0.w, q1.x, q1.y, q1.z, q1.w); // A, p4=p1b
        acc += xing1(q1.z, q1.w, q2.x, q2.y, q2.z, q2.w, q3.x, q3.y); // B, p4=p1c
        acc += xing1(q3.x, q3.y, q3.z, q3.w, q4.x, q4.y, q4.z, q4.w); // C, p4=p1d
        acc += xing1(q4.z, q4.w, q5.x, q5.y, q5.z, q5.w, tl.x, tl.y); // D, p4=next p1
        __syncthreads();   // before next row overwrites the buffer
    }

    // 64-lane wave reduce, then cross-wave via LDS
    for (int off = 32; off > 0; off >>= 1) acc += __shfl_down(acc, off);

    __shared__ float wsum[NTHREADS / 64];
    int lane = tid & 63;
    int wid  = tid >> 6;
    if (lane == 0) wsum[wid] = acc;
    __syncthreads();
    if (tid == 0) {
        float s = 0.0f;
        #pragma unroll
        for (int i = 0; i < NTHREADS / 64; ++i) s += wsum[i];
        partial[blockIdx.x] = s;
    }
}

__global__ __launch_bounds__(NTHREADS) void xing_final(const float* __restrict__ partial,
                                                       float* __restrict__ out,
                                                       int n, float invN) {
    float acc = 0.0f;
    for (int i = threadIdx.x; i < n; i += NTHREADS) acc += partial[i];
    for (int off = 32; off > 0; off >>= 1) acc += __shfl_down(acc, off);

    __shared__ float wsum[NTHREADS / 64];
    int lane = threadIdx.x & 63;
    int wid  = threadIdx.x >> 6;
    if (lane == 0) wsum[wid] = acc;
    __syncthreads();
    if (threadIdx.x == 0) {
        float s = 0.0f;
        #pragma unroll
        for (int i = 0; i < NTHREADS / 64; ++i) s += wsum[i];
        out[0] = s * invN;
    }
}

extern "C" void kernel_launch(void* const* d_in, const int* in_sizes, int n_in,
                              void* d_out, int out_size, void* d_ws, size_t ws_size,
                              hipStream_t stream) {
    const float* pts = (const float*)d_in[0];
    float* out = (float*)d_out;
    float* partial = (float*)d_ws;               // NBLOCKS floats = 8 KB

    int P = in_sizes[0] / ROW_FLOATS;            // 8192
    float invN = 1.0f / (float)((long long)P * 1024); // 1/2^23 exact

    xing_partial<<<NBLOCKS, NTHREADS, 0, stream>>>(pts, partial, P);
    xing_final<<<1, NTHREADS, 0, stream>>>(partial, out, NBLOCKS, invN);
}